// Round 11
// baseline (4445.219 us; speedup 1.0000x reference)
//
#include <hip/hip_runtime.h>
#include <hip/hip_bf16.h>

typedef __hip_bfloat16 bf16;
typedef __attribute__((ext_vector_type(8))) short short8;
typedef __attribute__((ext_vector_type(4))) short short4v;
typedef __attribute__((ext_vector_type(4))) float f32x4;

__device__ __forceinline__ bf16 f2b(float v){ return __float2bfloat16(v); }
__device__ __forceinline__ unsigned short bfbits(float v){
  union{ bf16 h; unsigned short u; } t; t.h = f2b(v); return t.u;
}
__device__ __forceinline__ float bs2f(short s){
  union{ unsigned u; float f; } t; t.u = ((unsigned)(unsigned short)s) << 16; return t.f;
}

// ---------------- weight repacks ----------------
__global__ void repack_tco(const float* __restrict__ w, float* __restrict__ o,
                           int Cout, int Cin, int KK){
  int i = blockIdx.x*256 + threadIdx.x;
  int total = Cout*Cin*KK;
  if (i >= total) return;
  int co = i / (Cin*KK);
  int r  = i - co*(Cin*KK);
  int ci = r / KK;
  int t  = r - ci*KK;
  o[((size_t)t*Cin + ci)*Cout + co] = w[i];
}

__global__ void repack_cto(const float* __restrict__ w, float* __restrict__ o,
                           int Cout, int Cin, int KK){
  int i = blockIdx.x*256 + threadIdx.x;
  int total = Cout*Cin*KK;
  if (i >= total) return;
  int co = i / (Cin*KK);
  int r  = i - co*(Cin*KK);
  int ci = r / KK;
  int t  = r - ci*KK;
  o[((size_t)ci*KK + t)*Cout + co] = w[i];
}

// w[Cout][Cin][16] f32 -> o[tap][Cout][Cin] bf16  (MFMA A-operand)
__global__ void repack_tcc_bf16(const float* __restrict__ w, short* __restrict__ o,
                                int Cout, int Cin){
  int i = blockIdx.x*256 + threadIdx.x;
  int total = Cout*Cin*16;
  if (i >= total) return;
  int co = i / (Cin*16);
  int r  = i - co*(Cin*16);
  int ci = r >> 4;
  int t  = r & 15;
  o[((size_t)t*Cout + co)*Cin + ci] = (short)bfbits(w[i]);
}

__global__ void cvt_bf16(const float* __restrict__ w, short* __restrict__ o, int n){
  int i = blockIdx.x*256 + threadIdx.x;
  if (i < n) o[i] = (short)bfbits(w[i]);
}

// ---------------- enc0: conv k=4 s=2 p=1, NCHW f32 in -> NHWC bf16 out ----------------
__global__ __launch_bounds__(256) void conv_enc0(
    const float* __restrict__ x, const float* __restrict__ wp,  // [tap][ci][co]
    const float* __restrict__ bias, short* __restrict__ y)      // NHWC [128][128][128]
{
  int t = blockIdx.x*256 + threadIdx.x;
  int oh  = t >> 5;
  int ow0 = (t & 31) * 4;
  int co0 = blockIdx.y * 8;
  int n   = blockIdx.z;
  float acc[8][4];
  #pragma unroll
  for (int j=0;j<8;j++){
    float bv = bias[co0+j];
    #pragma unroll
    for (int o=0;o<4;o++) acc[j][o] = bv;
  }
  const float* xn = x + (size_t)n*3*65536;
  #pragma unroll
  for (int ci=0; ci<3; ci++){
    const float* xc = xn + (size_t)ci*65536;
    #pragma unroll
    for (int kh=0; kh<4; kh++){
      int ih = 2*oh - 1 + kh;
      float xv[12];
      if ((unsigned)ih < 256u){
        #pragma unroll
        for (int c2=0; c2<6; c2++){
          int col = 2*ow0 - 2 + 2*c2;
          if (col >= 0 && col < 256){
            float2 v = *(const float2*)(xc + (size_t)ih*256 + col);
            xv[2*c2] = v.x; xv[2*c2+1] = v.y;
          } else { xv[2*c2] = 0.f; xv[2*c2+1] = 0.f; }
        }
      } else {
        #pragma unroll
        for (int k=0;k<12;k++) xv[k] = 0.f;
      }
      #pragma unroll
      for (int kw=0; kw<4; kw++){
        const float* wr = wp + (size_t)((kh*4+kw)*3 + ci)*128 + co0;
        #pragma unroll
        for (int j=0;j<8;j++){
          float wf = wr[j];
          #pragma unroll
          for (int o=0;o<4;o++)
            acc[j][o] = fmaf(xv[2*o+kw+1], wf, acc[j][o]);
        }
      }
    }
  }
  #pragma unroll
  for (int o=0;o<4;o++){
    short8 pk;
    #pragma unroll
    for (int j=0;j<8;j++) pk[j] = (short)bfbits(fmaxf(acc[j][o], 0.f));
    *(short8*)&y[(((size_t)n*128 + oh)*128 + (ow0+o))*128 + co0] = pk;
  }
}

// ---------------- enc1/enc2: conv k=4 s=2 p=1 MFMA, NHWC ----------------
// Block: 4 output rows x 32 output cols, 64 co (cs=4). 4 waves = 4 rows.
// Stage: input rows 8*by-1 .. 8*by+8 (10) x cols 2*j0-1 .. 2*j0+64 (66) x 32 ci.
__global__ __launch_bounds__(256) void conv_enc_mfma3(
    const short* __restrict__ x, const short* __restrict__ wb,
    const float* __restrict__ bias, short* __restrict__ y,
    int Cin, int Hin, int Win, int Cout)
{
  constexpr int CLS = 66;
  constexpr int CIP = 40;
  __shared__ __align__(16) short lds[10*CLS*CIP];

  int tid = threadIdx.x;
  int w = tid >> 6, lane = tid & 63;
  int n15 = lane & 15, quad = lane >> 4;
  int ob0 = blockIdx.y * 4;
  int j0  = blockIdx.x * 32;
  int nct = Cout >> 6;
  int ct  = blockIdx.z % nct;
  int nimg = blockIdx.z / nct;
  int co_base = ct*64;
  int Hout = Hin >> 1, Wout = Win >> 1;
  int ob = ob0 + w;
  int row_org = 2*ob0 - 1;
  int col_org = 2*j0 - 1;

  f32x4 acc[4][2];
  #pragma unroll
  for (int cs=0; cs<4; cs++){
    int cb = co_base + cs*16 + quad*4;
    f32x4 bv = {bias[cb], bias[cb+1], bias[cb+2], bias[cb+3]};
    acc[cs][0] = bv; acc[cs][1] = bv;
  }

  const short* xn = x + (size_t)nimg*Hin*Win*Cin;
  for (int ci0 = 0; ci0 < Cin; ci0 += 32){
    __syncthreads();
    for (int idx = tid; idx < 10*CLS*4; idx += 256){
      int r   = idx / (CLS*4);
      int rem = idx - r*(CLS*4);
      int c   = rem >> 2;
      int q4  = rem & 3;
      int gi = row_org + r, gj = col_org + c;
      short8 v = {0,0,0,0,0,0,0,0};
      if ((unsigned)gi < (unsigned)Hin && (unsigned)gj < (unsigned)Win)
        v = *(const short8*)(xn + ((size_t)gi*Win + gj)*Cin + ci0 + q4*8);
      *(short8*)&lds[(r*CLS + c)*CIP + q4*8] = v;
    }
    __syncthreads();
    #pragma unroll
    for (int kh=0; kh<4; kh++){
      short8 bfr[4][2];
      #pragma unroll
      for (int kw=0; kw<4; kw++)
        #pragma unroll
        for (int ss=0; ss<2; ss++){
          int c = 2*(ss*16 + n15) + kw;
          bfr[kw][ss] = *(const short8*)&lds[((2*w+kh)*CLS + c)*CIP + quad*8];
        }
      #pragma unroll
      for (int kw=0; kw<4; kw++){
        int tap = kh*4 + kw;
        const short* wt = wb + (size_t)(tap*Cout + co_base + n15)*Cin + ci0 + quad*8;
        #pragma unroll
        for (int cs=0; cs<4; cs++){
          short8 af = *(const short8*)(wt + (size_t)cs*16*Cin);
          #pragma unroll
          for (int ss=0; ss<2; ss++)
            acc[cs][ss] = __builtin_amdgcn_mfma_f32_16x16x32_bf16(af, bfr[kw][ss], acc[cs][ss], 0,0,0);
        }
      }
    }
  }
  #pragma unroll
  for (int cs=0; cs<4; cs++)
    #pragma unroll
    for (int ss=0; ss<2; ss++){
      int jj = j0 + ss*16 + n15;
      short4v pk;
      #pragma unroll
      for (int r=0;r<4;r++) pk[r] = (short)bfbits(fmaxf(acc[cs][ss][r], 0.f));
      *(short4v*)&y[(((size_t)nimg*Hout + ob)*Wout + jj)*Cout + co_base + cs*16 + quad*4] = pk;
    }
}

// ---------------- proj: 1x1 conv MFMA GEMM; z -> NCHW f32 (d_out) + NHWC f32 (ws) ----------------
__global__ __launch_bounds__(256) void proj_mfma(
    const short* __restrict__ x, const short* __restrict__ wb,
    const float* __restrict__ bias, float* __restrict__ z_nchw,
    float* __restrict__ z_nhwc)
{
  int tid = threadIdx.x;
  int w = tid >> 6, lane = tid & 63;
  int n15 = lane & 15, quad = lane >> 4;
  int sp0 = blockIdx.x*64 + w*16;
  int nimg = blockIdx.y;
  f32x4 acc[4];
  #pragma unroll
  for (int cs=0; cs<4; cs++){
    int cb = cs*16 + quad*4;
    acc[cs] = f32x4{bias[cb], bias[cb+1], bias[cb+2], bias[cb+3]};
  }
  const short* xs = x + ((size_t)nimg*1024 + sp0 + n15)*512;
  for (int ci0=0; ci0<512; ci0+=32){
    short8 bfr = *(const short8*)(xs + ci0 + quad*8);
    #pragma unroll
    for (int cs=0; cs<4; cs++){
      short8 af = *(const short8*)(wb + (size_t)(cs*16+n15)*512 + ci0 + quad*8);
      acc[cs] = __builtin_amdgcn_mfma_f32_16x16x32_bf16(af, bfr, acc[cs], 0,0,0);
    }
  }
  int sp = sp0 + n15;
  #pragma unroll
  for (int cs=0; cs<4; cs++){
    #pragma unroll
    for (int r=0;r<4;r++)
      z_nchw[(size_t)nimg*65536 + (size_t)(cs*16+quad*4+r)*1024 + sp] = acc[cs][r];
    *(f32x4*)&z_nhwc[((size_t)nimg*1024 + sp)*64 + cs*16 + quad*4] = acc[cs];
  }
}

// ---------------- VQ: per-wave argmin over 1024 codes ----------------
__global__ void vq_argmin(const float* __restrict__ zf, const float* __restrict__ cbf,
                          float* __restrict__ zq, short* __restrict__ zqst)
{
  __shared__ float lz[4][64];
  int t = threadIdx.x;
  int q = t >> 6, l = t & 63;
  int p = blockIdx.x*4 + q;
  int n = p >> 10, hw = p & 1023;
  size_t nhbase = ((size_t)n*1024 + hw)*64;
  float zl = zf[nhbase + l];
  lz[q][l] = zl;
  __syncthreads();
  float best = 3.0e38f; int bi = 0;
  const float* zv = &lz[q][0];
  for (int c = l; c < 1024; c += 64){
    const float4* row = reinterpret_cast<const float4*>(cbf + (size_t)c*64);
    float d = 0.f;
    #pragma unroll
    for (int v4 = 0; v4 < 16; v4++){
      float4 cv = row[v4];
      int j0 = v4*4;
      float d0 = zv[j0+0]-cv.x; d = fmaf(d0,d0,d);
      float d1 = zv[j0+1]-cv.y; d = fmaf(d1,d1,d);
      float d2 = zv[j0+2]-cv.z; d = fmaf(d2,d2,d);
      float d3 = zv[j0+3]-cv.w; d = fmaf(d3,d3,d);
    }
    if (d < best){ best = d; bi = c; }
  }
  #pragma unroll
  for (int off = 32; off > 0; off >>= 1){
    float od = __shfl_down(best, off, 64);
    int   oi = __shfl_down(bi,  off, 64);
    if (od < best || (od == best && oi < bi)){ best = od; bi = oi; }
  }
  bi = __shfl(bi, 0, 64);
  float qv = cbf[(size_t)bi*64 + l];
  zq[(size_t)n*65536 + (size_t)l*1024 + hw] = qv;
  zqst[nhbase + l] = (short)bfbits(zl + (qv - zl));
}

// ---------------- decoder: convT k=4 s=2 MFMA, NHWC, cs=4, 4-way spatial waves ----------------
// RB input rows per block, CG=4/RB col-groups of 32; 64 co per block.
template<int RB>
__global__ __launch_bounds__(256) void convT_mfma3(
    const short* __restrict__ x, const short* __restrict__ wb,
    const float* __restrict__ bias, short* __restrict__ y,
    int Cin, int Hin, int Win, int Cout, int relu)
{
  constexpr int CG  = 4/RB;
  constexpr int CLS = CG*32 + 2;
  constexpr int CIP = 40;
  __shared__ __align__(16) short lds[(RB+2)*CLS*CIP];

  int tid = threadIdx.x;
  int w = tid >> 6, lane = tid & 63;
  int wr = w / CG, wc = w % CG;
  int n15 = lane & 15, quad = lane >> 4;
  int ib0 = blockIdx.y * RB;
  int j0  = blockIdx.x * (CG*32);
  int nct = Cout >> 6;
  int ct  = blockIdx.z % nct;
  int nimg = blockIdx.z / nct;
  int co_base = ct*64;
  int ib = ib0 + wr;                 // this wave's input row
  int jw = j0 + wc*32;               // this wave's col base

  f32x4 acc[4][2][4];   // [cs][ss][parity]
  #pragma unroll
  for (int cs=0; cs<4; cs++){
    int cb = co_base + cs*16 + quad*4;
    f32x4 bv = {bias[cb], bias[cb+1], bias[cb+2], bias[cb+3]};
    #pragma unroll
    for (int ss=0; ss<2; ss++)
      #pragma unroll
      for (int p=0;p<4;p++) acc[cs][ss][p] = bv;
  }

  const short* xn = x + (size_t)nimg*Hin*Win*Cin;
  for (int ci0 = 0; ci0 < Cin; ci0 += 32){
    __syncthreads();
    for (int idx = tid; idx < (RB+2)*CLS*4; idx += 256){
      int r   = idx / (CLS*4);
      int rem = idx - r*(CLS*4);
      int c   = rem >> 2;
      int q4  = rem & 3;
      int gi = ib0 - 1 + r, gj = j0 - 1 + c;
      short8 v = {0,0,0,0,0,0,0,0};
      if ((unsigned)gi < (unsigned)Hin && (unsigned)gj < (unsigned)Win)
        v = *(const short8*)(xn + ((size_t)gi*Win + gj)*Cin + ci0 + q4*8);
      *(short8*)&lds[(r*CLS + c)*CIP + q4*8] = v;
    }
    __syncthreads();
    short8 bfr[9][2];
    #pragma unroll
    for (int dr=0; dr<3; dr++)
      #pragma unroll
      for (int dc=0; dc<3; dc++)
        #pragma unroll
        for (int ss=0; ss<2; ss++){
          int c = wc*32 + ss*16 + n15 + dc;
          bfr[dr*3+dc][ss] = *(const short8*)&lds[((wr+dr)*CLS + c)*CIP + quad*8];
        }
    #pragma unroll
    for (int ph=0; ph<2; ph++)
      #pragma unroll
      for (int pw=0; pw<2; pw++){
        int p = ph*2 + pw;
        #pragma unroll
        for (int u=0; u<2; u++)
          #pragma unroll
          for (int v=0; v<2; v++){
            int tap  = (ph + 2*u)*4 + (pw + 2*v);
            int sidx = (u + ph)*3 + (v + pw);
            const short* wt = wb + (size_t)(tap*Cout + co_base + n15)*Cin + ci0 + quad*8;
            #pragma unroll
            for (int cs=0; cs<4; cs++){
              short8 af = *(const short8*)(wt + (size_t)cs*16*Cin);
              #pragma unroll
              for (int ss=0; ss<2; ss++)
                acc[cs][ss][p] = __builtin_amdgcn_mfma_f32_16x16x32_bf16(af, bfr[sidx][ss], acc[cs][ss][p], 0,0,0);
            }
          }
      }
  }
  int Hout = Hin*2, Wout = Win*2;
  #pragma unroll
  for (int cs=0; cs<4; cs++)
    #pragma unroll
    for (int ss=0; ss<2; ss++){
      int jj = jw + ss*16 + n15;
      #pragma unroll
      for (int ph=0; ph<2; ph++)
        #pragma unroll
        for (int pw=0; pw<2; pw++){
          short4v pk;
          #pragma unroll
          for (int r=0;r<4;r++){
            float v2 = acc[cs][ss][ph*2+pw][r];
            if (relu) v2 = fmaxf(v2, 0.f);
            pk[r] = (short)bfbits(v2);
          }
          *(short4v*)&y[(((size_t)nimg*Hout + 2*ib+ph)*Wout + 2*jj+pw)*Cout + co_base + cs*16 + quad*4] = pk;
        }
    }
}

// ---------------- out conv: 3x3 p=1 s=1, NHWC in -> NCHW f32 out ----------------
__global__ __launch_bounds__(256) void conv3x3_out3(
    const short* __restrict__ x, const float* __restrict__ wct,  // [ci][9][3]
    const float* __restrict__ bias, float* __restrict__ y)
{
  __shared__ __align__(16) short xl[6*66*16];
  int tid = threadIdx.x;
  int row = tid >> 6;
  int col = tid & 63;
  int j0 = blockIdx.x*64;
  int r0 = blockIdx.y*4;
  int n  = blockIdx.z;
  const short* xn = x + (size_t)n*65536*128;
  float acc[3] = {bias[0], bias[1], bias[2]};
  for (int g=0; g<8; g++){
    int cig = g*16;
    __syncthreads();
    for (int idx = tid; idx < 792; idx += 256){
      int r = idx / 132;
      int rem = idx - r*132;
      int c = rem >> 1;
      int h = rem & 1;
      int gi = r0 - 1 + r, gj = j0 - 1 + c;
      short8 v = {0,0,0,0,0,0,0,0};
      if ((unsigned)gi < 256u && (unsigned)gj < 256u)
        v = *(const short8*)(xn + ((size_t)gi*256 + gj)*128 + cig + h*8);
      *(short8*)&xl[(r*66 + c)*16 + h*8] = v;
    }
    __syncthreads();
    #pragma unroll
    for (int half=0; half<2; half++){
      short8 xv[9];
      #pragma unroll
      for (int dr=0; dr<3; dr++)
        #pragma unroll
        for (int dc=0; dc<3; dc++)
          xv[dr*3+dc] = *(const short8*)&xl[((row+dr)*66 + col+dc)*16 + half*8];
      #pragma unroll
      for (int k=0;k<8;k++){
        const float* wr = wct + (size_t)(cig + half*8 + k)*27;
        #pragma unroll
        for (int tp=0; tp<9; tp++){
          float xf = bs2f(xv[tp][k]);
          acc[0] = fmaf(xf, wr[tp*3+0], acc[0]);
          acc[1] = fmaf(xf, wr[tp*3+1], acc[1]);
          acc[2] = fmaf(xf, wr[tp*3+2], acc[2]);
        }
      }
    }
  }
  size_t obase = (size_t)n*3*65536 + (size_t)(r0+row)*256 + j0 + col;
  y[obase]          = acc[0];
  y[obase + 65536]  = acc[1];
  y[obase + 131072] = acc[2];
}

// ---------------- workspace layout (bytes) ----------------
static const size_t W_WENC0  = 0;           //  24,576 f32 [tap][ci][co]
static const size_t W_WPROJB = 24576;       //  65,536 bf16 [co][ci]
static const size_t W_WOUT   = 90112;       //  13,824 f32 [ci][tap][co]
static const size_t W_E1B    = 103936;      //  1,048,576 bf16 [tap][co][ci]
static const size_t W_E2B    = 1152512;     //  4,194,304
static const size_t W_D0B    = 5346816;     //  1,048,576
static const size_t W_D1B    = 6395392;     //  4,194,304
static const size_t W_D2B    = 10589696;    //  1,048,576
static const size_t W_BYTES  = 11638272;
static const size_t PER_IMG = 29753344;

extern "C" void kernel_launch(void* const* d_in, const int* in_sizes, int n_in,
                              void* d_out, int out_size, void* d_ws, size_t ws_size,
                              hipStream_t stream)
{
  const float* x      = (const float*)d_in[0];
  const float* enc_w0 = (const float*)d_in[1];
  const float* enc_b0 = (const float*)d_in[2];
  const float* enc_w1 = (const float*)d_in[3];
  const float* enc_b1 = (const float*)d_in[4];
  const float* enc_w2 = (const float*)d_in[5];
  const float* enc_b2 = (const float*)d_in[6];
  const float* proj_w = (const float*)d_in[7];
  const float* proj_b = (const float*)d_in[8];
  const float* dec_w0 = (const float*)d_in[9];
  const float* dec_b0 = (const float*)d_in[10];
  const float* dec_w1 = (const float*)d_in[11];
  const float* dec_b1 = (const float*)d_in[12];
  const float* dec_w2 = (const float*)d_in[13];
  const float* dec_b2 = (const float*)d_in[14];
  const float* out_w  = (const float*)d_in[15];
  const float* out_b  = (const float*)d_in[16];
  const float* cb     = (const float*)d_in[17];

  float* out    = (float*)d_out;
  float* recon  = out;
  float* z_out  = out + 3145728;
  float* zq_out = out + 4194304;

  char* ws = (char*)d_ws;
  float* wenc0  = (float*)(ws + W_WENC0);
  short* wprojb = (short*)(ws + W_WPROJB);
  float* wout   = (float*)(ws + W_WOUT);
  short* we1b   = (short*)(ws + W_E1B);
  short* we2b   = (short*)(ws + W_E2B);
  short* wd0b   = (short*)(ws + W_D0B);
  short* wd1b   = (short*)(ws + W_D1B);
  short* wd2b   = (short*)(ws + W_D2B);

  int B = 16;
  while (B > 1 && W_BYTES + (size_t)B*PER_IMG > ws_size) B >>= 1;

  char* act = ws + W_BYTES;
  size_t szA  = (size_t)B*16777216;
  size_t szBg = (size_t)B*8388608;
  size_t szC  = (size_t)B*4194304;
  short* h0  = (short*)(act);
  short* d2  = (short*)(act);
  short* h1  = (short*)(act + szA);
  short* d1  = (short*)(act + szA);
  short* h2  = (short*)(act + szA + szBg);
  short* d0  = (short*)(act + szA + szBg);
  float* zf  = (float*)(act + szA + szBg + szC);
  short* zqs = (short*)(act + szA + szBg + szC + (size_t)B*262144);

  auto nb = [](int total){ return dim3((unsigned)((total + 255) / 256)); };

  repack_tco<<<nb(128*3*16),  256, 0, stream>>>(enc_w0, wenc0, 128, 3, 16);
  cvt_bf16<<<nb(32768),       256, 0, stream>>>(proj_w, wprojb, 32768);
  repack_cto<<<nb(3*128*9),   256, 0, stream>>>(out_w, wout, 3, 128, 9);
  repack_tcc_bf16<<<nb(256*128*16),256, 0, stream>>>(enc_w1, we1b, 256, 128);
  repack_tcc_bf16<<<nb(512*256*16),256, 0, stream>>>(enc_w2, we2b, 512, 256);
  repack_tcc_bf16<<<nb(512*64*16), 256, 0, stream>>>(dec_w0, wd0b, 512, 64);
  repack_tcc_bf16<<<nb(256*512*16),256, 0, stream>>>(dec_w1, wd1b, 256, 512);
  repack_tcc_bf16<<<nb(128*256*16),256, 0, stream>>>(dec_w2, wd2b, 128, 256);

  for (int n0 = 0; n0 < 16; n0 += B){
    const float* xc  = x      + (size_t)n0*3*65536;
    float* reconc    = recon  + (size_t)n0*3*65536;
    float* z_outc    = z_out  + (size_t)n0*65536;
    float* zq_outc   = zq_out + (size_t)n0*65536;

    // encoder (NHWC activations)
    conv_enc0<<<dim3(16,16,B), 256, 0, stream>>>(xc, wenc0, enc_b0, h0);
    conv_enc_mfma3<<<dim3(2, 16, 4*B), 256, 0, stream>>>(
        h0, we1b, enc_b1, h1, 128, 128, 128, 256);
    conv_enc_mfma3<<<dim3(1, 8, 8*B), 256, 0, stream>>>(
        h1, we2b, enc_b2, h2, 256, 64, 64, 512);
    proj_mfma<<<dim3(16, B), 256, 0, stream>>>(h2, wprojb, proj_b, z_outc, zf);

    vq_argmin<<<dim3(256*B), 256, 0, stream>>>(zf, cb, zq_outc, zqs);

    // decoder (NHWC)
    convT_mfma3<4><<<dim3(1, 8, 8*B), 256, 0, stream>>>(
        zqs, wd0b, dec_b0, d0, 64, 32, 32, 512, 1);
    convT_mfma3<2><<<dim3(1, 32, 4*B), 256, 0, stream>>>(
        d0, wd1b, dec_b1, d1, 512, 64, 64, 256, 1);
    convT_mfma3<2><<<dim3(2, 64, 2*B), 256, 0, stream>>>(
        d1, wd2b, dec_b2, d2, 256, 128, 128, 128, 1);

    conv3x3_out3<<<dim3(4, 64, B), 256, 0, stream>>>(d2, wout, out_b, reconc);
  }
}